// Round 2
// baseline (139.142 us; speedup 1.0000x reference)
//
#include <hip/hip_runtime.h>

// BilinearPooling: out[i,k] = mean_j(conv1[i,j]) * conv2[i,k]
// B=256, J=K=14*14*256=50176. Memory-bound: 154 MB logical traffic.
//
// Fused single-dispatch design:
//  - 256 blocks (1/row, 1/CU) x 1024 threads.
//  - Each thread STAGES its 12 conv2 float4s in registers, issue-interleaved
//    1:1 with the conv1 reduction loads -> both 51.4 MB read streams are in
//    flight concurrently instead of back-to-back (the round-0/1 serialization
//    was the 3.6 TB/s effective-BW cap).
//  - sched_barrier(0) pins issue order so the compiler can't sink the staged
//    loads below the reduction.
//  - After the block-wide mean, scale the staged registers and store with
//    nontemporal stores (out is never re-read; don't evict L3-resident inputs).

typedef float f32x4 __attribute__((ext_vector_type(4)));

#define ROW_ELEMS 50176
#define ROW_VEC   12544               // float4 per row
#define THREADS   1024
#define FULL_IT   12                  // 12*1024 = 12288 float4
#define TAIL_BASE (FULL_IT * THREADS) // 12288
#define TAIL_N    (ROW_VEC - TAIL_BASE) // 256 -> handled by tid < 256

__global__ __launch_bounds__(THREADS)
void bp_fused_kernel(const f32x4* __restrict__ c1,
                     const f32x4* __restrict__ c2,
                     f32x4* __restrict__ out) {
    const int tid = threadIdx.x;
    const size_t rb = (size_t)blockIdx.x * ROW_VEC;
    const f32x4* __restrict__ r1 = c1 + rb;
    const f32x4* __restrict__ r2 = c2 + rb;
    f32x4* __restrict__ ro = out + rb;

    f32x4 st[FULL_IT];   // conv2 staged in registers (indices static after unroll)
    float s = 0.0f;

    // Interleaved dual-stream read: conv2 -> registers, conv1 -> reduction.
    #pragma unroll
    for (int i = 0; i < FULL_IT; ++i) {
        st[i] = r2[tid + i * THREADS];
        f32x4 v = r1[tid + i * THREADS];
        s += (v[0] + v[1]) + (v[2] + v[3]);
    }

    // Tail: 256 remaining float4 (indices 12288..12543), threads 0..255.
    f32x4 st_t;
    const bool has_tail = (tid < TAIL_N);
    if (has_tail) {
        st_t = r2[TAIL_BASE + tid];
        f32x4 v = r1[TAIL_BASE + tid];
        s += (v[0] + v[1]) + (v[2] + v[3]);
    }

    // Pin all load issues above this point (don't let the scheduler sink the
    // staged conv2 loads below the reduction chain).
    __builtin_amdgcn_sched_barrier(0);

    // Wave-64 butterfly reduction.
    #pragma unroll
    for (int off = 32; off > 0; off >>= 1)
        s += __shfl_down(s, off, 64);

    __shared__ float wsum[THREADS / 64];
    __shared__ float mean_s;
    const int lane = tid & 63;
    const int wid  = tid >> 6;
    if (lane == 0) wsum[wid] = s;
    __syncthreads();
    if (tid == 0) {
        float t = 0.0f;
        #pragma unroll
        for (int i = 0; i < THREADS / 64; ++i) t += wsum[i];
        mean_s = t * (1.0f / (float)ROW_ELEMS);
    }
    __syncthreads();
    const float m = mean_s;

    // Scale staged registers, nontemporal store.
    #pragma unroll
    for (int i = 0; i < FULL_IT; ++i) {
        f32x4 v = st[i];
        v *= m;
        __builtin_nontemporal_store(v, &ro[tid + i * THREADS]);
    }
    if (has_tail) {
        f32x4 v = st_t;
        v *= m;
        __builtin_nontemporal_store(v, &ro[TAIL_BASE + tid]);
    }
}

extern "C" void kernel_launch(void* const* d_in, const int* in_sizes, int n_in,
                              void* d_out, int out_size, void* d_ws, size_t ws_size,
                              hipStream_t stream) {
    const f32x4* c1 = (const f32x4*)d_in[0];
    const f32x4* c2 = (const f32x4*)d_in[1];
    f32x4* out = (f32x4*)d_out;

    bp_fused_kernel<<<256, THREADS, 0, stream>>>(c1, c2, out);
}

// Round 5
// 139.122 us; speedup vs baseline: 1.0001x; 1.0001x over previous
//
#include <hip/hip_runtime.h>

// BilinearPooling: out[i,k] = mean_j(conv1[i,j]) * conv2[i,k]
// B=256, J=K=14*14*256=50176. Memory-bound: 154 MB logical traffic.
//
// Round-5 (= round-3/4 resubmit; broker timed out twice, kernel never ran):
// FORCED dual-stream read overlap.
// Round-2's staging was silently killed (VGPR_Count=48 -> compiler sank the
// conv2 loads below the barrier; kernel degenerated to serial two-phase).
// This version pins each staged float4 live across the barrier with an empty
// read-write inline asm, so both 51.4 MB read streams are genuinely in flight
// concurrently before the reduction barrier; epilogue is scale + NT store.

typedef float f32x4 __attribute__((ext_vector_type(4)));

#define ROW_ELEMS 50176
#define ROW_VEC   12544               // float4 per row
#define THREADS   1024
#define FULL_IT   12                  // 12*1024 = 12288 float4
#define TAIL_BASE (FULL_IT * THREADS) // 12288
#define TAIL_N    (ROW_VEC - TAIL_BASE) // 256 -> threads 0..255

__global__ __launch_bounds__(THREADS)
void bp_fused_kernel(const f32x4* __restrict__ c1,
                     const f32x4* __restrict__ c2,
                     f32x4* __restrict__ out) {
    const int tid = threadIdx.x;
    const size_t rb = (size_t)blockIdx.x * ROW_VEC;
    const f32x4* __restrict__ r1 = c1 + rb;
    const f32x4* __restrict__ r2 = c2 + rb;
    f32x4* __restrict__ ro = out + rb;

    f32x4 st[FULL_IT];
    float s = 0.0f;

    // Interleaved dual-stream read: conv2 -> registers, conv1 -> reduction.
    #pragma unroll
    for (int i = 0; i < FULL_IT; ++i) {
        st[i] = r2[tid + i * THREADS];
        f32x4 v = r1[tid + i * THREADS];
        s += (v[0] + v[1]) + (v[2] + v[3]);
    }

    f32x4 st_t;
    const bool has_tail = (tid < TAIL_N);
    if (has_tail) {
        st_t = r2[TAIL_BASE + tid];
        f32x4 v = r1[TAIL_BASE + tid];
        s += (v[0] + v[1]) + (v[2] + v[3]);
    } else {
        st_t = f32x4{0.f, 0.f, 0.f, 0.f};
    }

    // FORCE the staged conv2 values live here (before the barrier). The asm
    // reads each value (load must complete before this point in data-flow)
    // and "writes" it (epilogue must use the register, not a post-barrier
    // reload). This is what round-2 was missing.
    #pragma unroll
    for (int i = 0; i < FULL_IT; ++i)
        asm volatile("" : "+v"(st[i]));
    asm volatile("" : "+v"(st_t));

    // Wave-64 butterfly reduction.
    #pragma unroll
    for (int off = 32; off > 0; off >>= 1)
        s += __shfl_down(s, off, 64);

    __shared__ float wsum[THREADS / 64];
    __shared__ float mean_s;
    const int lane = tid & 63;
    const int wid  = tid >> 6;
    if (lane == 0) wsum[wid] = s;
    __syncthreads();
    if (tid == 0) {
        float t = 0.0f;
        #pragma unroll
        for (int i = 0; i < THREADS / 64; ++i) t += wsum[i];
        mean_s = t * (1.0f / (float)ROW_ELEMS);
    }
    __syncthreads();
    const float m = mean_s;

    // Epilogue: scale staged registers, nontemporal store.
    #pragma unroll
    for (int i = 0; i < FULL_IT; ++i) {
        f32x4 v = st[i];
        v *= m;
        __builtin_nontemporal_store(v, &ro[tid + i * THREADS]);
    }
    if (has_tail) {
        f32x4 v = st_t;
        v *= m;
        __builtin_nontemporal_store(v, &ro[TAIL_BASE + tid]);
    }
}

extern "C" void kernel_launch(void* const* d_in, const int* in_sizes, int n_in,
                              void* d_out, int out_size, void* d_ws, size_t ws_size,
                              hipStream_t stream) {
    const f32x4* c1 = (const f32x4*)d_in[0];
    const f32x4* c2 = (const f32x4*)d_in[1];
    f32x4* out = (f32x4*)d_out;

    bp_fused_kernel<<<256, THREADS, 0, stream>>>(c1, c2, out);
}